// Round 1
// baseline (226.497 us; speedup 1.0000x reference)
//
#include <hip/hip_runtime.h>

typedef unsigned short u16;

#define NGRAPH 16
#define SEQ    1024
#define DIM    128
#define NHEAD  2
#define HDIM   64
#define KPOS   20
#define NTOT   (NGRAPH*SEQ)     // 16384
#define QKVD   (3*DIM)          // 384

// ---------- bf16 helpers ----------------------------------------------------
__device__ __forceinline__ float bf2f(u16 u) {
    return __uint_as_float(((unsigned int)u) << 16);
}
__device__ __forceinline__ u16 f2bf(float f) {
    unsigned int u = __float_as_uint(f);
    u += 0x7fffu + ((u >> 16) & 1u);   // RNE
    return (u16)(u >> 16);
}

// ---------- dtype-adaptive input loads (fbf=1: bf16, fbf=0: f32) -----------
__device__ __forceinline__ float ld1(const void* p, int fbf, size_t i) {
    return fbf ? bf2f(((const u16*)p)[i]) : ((const float*)p)[i];
}
// 8 contiguous weights -> packed bf16x8 (as float4 bit pattern)
__device__ __forceinline__ float4 ldw8(const void* W, int fbf, size_t i) {
    if (fbf) return *(const float4*)((const u16*)W + i);
    const float* q = (const float*)W + i;
    float4 a = *(const float4*)q, b = *(const float4*)(q + 4);
    float4 r;
    u16* d = (u16*)&r;
    d[0]=f2bf(a.x); d[1]=f2bf(a.y); d[2]=f2bf(a.z); d[3]=f2bf(a.w);
    d[4]=f2bf(b.x); d[5]=f2bf(b.y); d[6]=f2bf(b.z); d[7]=f2bf(b.w);
    return r;
}

// ---------- K0: dtype detection --------------------------------------------
__global__ void detect_kernel(const u16* __restrict__ x, int* __restrict__ flag) {
    if (threadIdx.x == 0 && blockIdx.x == 0) {
        int ok = 1;
        for (int i = 0; i < 256; i += 2) {
            unsigned e = (x[i] >> 7) & 0xFF;
            if (e < 60u || e > 180u) ok = 0;
        }
        *flag = ok;
    }
}

// ---------- K1: h0 = x + pos_enc @ pe_w.T + pe_b  (bf16, strided slots) ----
__global__ __launch_bounds__(256)
void pe_kernel(const void* __restrict__ x, const void* __restrict__ pos,
               const void* __restrict__ pe_w, const void* __restrict__ pe_b,
               u16* __restrict__ h0, const int* __restrict__ flag) {
    int fbf = *flag;
    __shared__ float wsh[DIM][KPOS + 1];
    int t = threadIdx.x;
    for (int i = t; i < DIM * KPOS; i += 256)
        wsh[i / KPOS][i % KPOS] = ld1(pe_w, fbf, i);
    __syncthreads();
    int row = blockIdx.x * 2 + (t >> 7), d = t & 127;
    float acc = 0.f;
#pragma unroll
    for (int k = 0; k < KPOS; ++k)
        acc += ld1(pos, fbf, (size_t)row * KPOS + k) * wsh[d][k];
    int rs = fbf ? 128 : 256;   // h0 row slot stride (u16 units)
    h0[(size_t)row * rs + d] =
        f2bf(ld1(x, fbf, (size_t)row * DIM + d) + acc + ld1(pe_b, fbf, d));
}

typedef __attribute__((ext_vector_type(8))) short bf16x8;
typedef __attribute__((ext_vector_type(4))) float f32x4;

// ---------- unified MFMA GEMM: out = A @ W^T (+epilogue) -------------------
// Block 256 = 4 waves; tile 64 rows x 128 cols; K staged 128 at a time
// (NK chunks of 128), register-prefetched. One barrier per chunk.
// EPI 0: +bias -> bf16 ws     EPI 1: +bias,relu -> bf16 ws
// EPI 2: +bias+resid+LN -> h01 slots   EPI 3: +bias+resid+LN -> final out
// A always bf16; AstrIn<0 means "h01 slot stride" (fbf?128:256).
template<int EPI, int NK>
__global__ __launch_bounds__(256)
void mgemm_kernel(const u16* __restrict__ A, const void* __restrict__ W,
                  const void* __restrict__ bias, const u16* __restrict__ resid,
                  const void* __restrict__ lng, const void* __restrict__ lnb,
                  void* __restrict__ outp, int Mtot, int AstrIn,
                  int arow0, int orow0, const int* __restrict__ flag) {
    const int K = NK * 128;
    int fbf  = *flag;
    int rs   = fbf ? 128 : 256;
    int Astr = (AstrIn < 0) ? rs : AstrIn;
    __shared__ u16 Ash[64][136];    // [row][k] (+8 pad)
    __shared__ u16 Wsh[128][136];   // [col][k]
    int t = threadIdx.x;
    int w = t >> 6, lane = t & 63, l16 = lane & 15, quad = lane >> 4;
    int n0 = blockIdx.x * 64;
    int m0 = blockIdx.y * 128;
    f32x4 acc[8] = {};
    float4 aR[4], wR[8];
    // prefetch chunk 0
#pragma unroll
    for (int i = 0; i < 4; ++i) {
        int idx = t + i * 256;
        int row = idx >> 4, k8 = (idx & 15) * 8;
        aR[i] = *(const float4*)&A[(size_t)(arow0 + n0 + row) * Astr + k8];
    }
#pragma unroll
    for (int i = 0; i < 8; ++i) {
        int idx = t + i * 256;
        int row = idx >> 4, k8 = (idx & 15) * 8;
        wR[i] = ldw8(W, fbf, (size_t)(m0 + row) * K + k8);
    }
#pragma unroll 1
    for (int c = 0; c < NK; ++c) {
        // regs -> LDS
#pragma unroll
        for (int i = 0; i < 4; ++i) {
            int idx = t + i * 256;
            *(float4*)&Ash[idx >> 4][(idx & 15) * 8] = aR[i];
        }
#pragma unroll
        for (int i = 0; i < 8; ++i) {
            int idx = t + i * 256;
            *(float4*)&Wsh[idx >> 4][(idx & 15) * 8] = wR[i];
        }
        __syncthreads();
        if (c + 1 < NK) {   // prefetch next chunk (overlaps MFMA below)
            int kc = (c + 1) * 128;
#pragma unroll
            for (int i = 0; i < 4; ++i) {
                int idx = t + i * 256;
                int row = idx >> 4, k8 = (idx & 15) * 8;
                aR[i] = *(const float4*)&A[(size_t)(arow0 + n0 + row) * Astr + kc + k8];
            }
#pragma unroll
            for (int i = 0; i < 8; ++i) {
                int idx = t + i * 256;
                int row = idx >> 4, k8 = (idx & 15) * 8;
                wR[i] = ldw8(W, fbf, (size_t)(m0 + row) * K + kc + k8);
            }
        }
#pragma unroll
        for (int kk = 0; kk < 4; ++kk) {
            bf16x8 af = *(const bf16x8*)&Ash[w * 16 + l16][kk * 32 + quad * 8];
#pragma unroll
            for (int s = 0; s < 8; ++s) {
                bf16x8 bf = *(const bf16x8*)&Wsh[s * 16 + l16][kk * 32 + quad * 8];
                acc[s] = __builtin_amdgcn_mfma_f32_16x16x32_bf16(af, bf, acc[s], 0, 0, 0);
            }
        }
        if (c + 1 < NK) __syncthreads();
    }
    // ---- epilogue ----
    float bb[8];
#pragma unroll
    for (int s = 0; s < 8; ++s) bb[s] = ld1(bias, fbf, m0 + s * 16 + l16);
    float gg[8], be[8];
    if (EPI >= 2) {
#pragma unroll
        for (int s = 0; s < 8; ++s) {
            gg[s] = ld1(lng, fbf, s * 16 + l16);
            be[s] = ld1(lnb, fbf, s * 16 + l16);
        }
    }
#pragma unroll
    for (int r = 0; r < 4; ++r) {
        int lr = w * 16 + quad * 4 + r;
        float v[8];
#pragma unroll
        for (int s = 0; s < 8; ++s) {
            v[s] = acc[s][r] + bb[s];
            if (EPI == 1) v[s] = fmaxf(v[s], 0.f);
        }
        if (EPI <= 1) {
            u16* o = (u16*)outp;
#pragma unroll
            for (int s = 0; s < 8; ++s)
                o[(size_t)(n0 + lr) * Mtot + m0 + s * 16 + l16] = f2bf(v[s]);
        } else {
            size_t rg = (size_t)(orow0 + n0 + lr);
#pragma unroll
            for (int s = 0; s < 8; ++s)
                v[s] += bf2f(resid[rg * rs + s * 16 + l16]);
            float sm = 0.f, sq = 0.f;
#pragma unroll
            for (int s = 0; s < 8; ++s) { sm += v[s]; sq += v[s] * v[s]; }
#pragma unroll
            for (int off = 1; off < 16; off <<= 1) {
                sm += __shfl_xor(sm, off, 64);
                sq += __shfl_xor(sq, off, 64);
            }
            float mu  = sm * (1.f / DIM);
            float var = fmaxf(sq * (1.f / DIM) - mu * mu, 0.f);
            float rsq = rsqrtf(var + 1e-5f);
            if (EPI == 2) {
                u16* o = (u16*)outp;
#pragma unroll
                for (int s = 0; s < 8; ++s)
                    o[rg * rs + s * 16 + l16] =
                        f2bf((v[s] - mu) * rsq * gg[s] + be[s]);
            } else {
                if (fbf) {
                    u16* o = (u16*)outp;
#pragma unroll
                    for (int s = 0; s < 8; ++s)
                        o[rg * 128 + s * 16 + l16] =
                            f2bf((v[s] - mu) * rsq * gg[s] + be[s]);
                } else {
                    float* o = (float*)outp;
#pragma unroll
                    for (int s = 0; s < 8; ++s)
                        o[rg * 128 + s * 16 + l16] =
                            (v[s] - mu) * rsq * gg[s] + be[s];
                }
            }
        }
    }
}

// ---------- K3: flash attention, MFMA bf16, in-block KV-split x2 -----------
// Grid = ngh*16 blocks of 512 threads (8 waves). Waves 0-3 (team 0) process
// KV tiles 0..7, waves 4-7 (team 1) process tiles 8..15, over the SAME 64-row
// Q tile, each team with private K/V/P LDS buffers and its own online-softmax
// state. Partials merged through LDS at the end (team 1 -> team 0).
// Rationale: grid 512 = only 2 blocks/CU; 4-wave blocks capped occupancy at
// 8 waves/CU (18% measured, latency-bound: MfmaUtil 6.7%, VALU 29%, HBM 4.5%).
// 8-wave blocks double resident waves/CU to 16 without a combine kernel.
// For ngh>=8, blockIdx is XCD-swizzled so all 16 q-tiles of one graph-head
// land on one XCD (its K/V then stays in that XCD's L2).
__global__ __launch_bounds__(512)
void attn_kernel(const u16* __restrict__ qkv, u16* __restrict__ ctx) {
    // LDS layout (bytes):
    //   [    0,  9216) Qsh   [64][72] u16          (shared by both teams)
    //   [ 9216, 36864) team0: Ksh/VshT/Psh [64][72] u16 each
    //   [36864, 64512) team1: Ksh/VshT/Psh
    //   merge overlay @36864: Osh f32[64][68] + Msh[64] + Lsh[64]
    //   (overlays team1 K/V; written only after team1's last K/V read)
    __shared__ __align__(16) char smem[64512];
    int t    = threadIdx.x;
    int team = t >> 8;          // 0 or 1
    int tt   = t & 255;         // thread id within team
    int w    = tt >> 6;         // wave within team (0..3)
    int lane = tt & 63;
    int l16  = lane & 15;
    int quad = lane >> 4;
    u16 (*Qsh)[72]   = (u16(*)[72])(smem);
    u16 (*Ksh)[72]   = (u16(*)[72])(smem +  9216 + team * 27648);
    u16 (*VshT)[72]  = (u16(*)[72])(smem + 18432 + team * 27648);
    u16 (*Psh)[72]   = (u16(*)[72])(smem + 27648 + team * 27648);
    float (*Osh)[68] = (float(*)[68])(smem + 36864);
    float* Msh       = (float*)(smem + 36864 + 64 * 68 * 4);
    float* Lsh       = Msh + 64;

    int L = blockIdx.x;
    int ngh = gridDim.x >> 4;
    int qt, gh;
    if (ngh >= 8) {           // XCD swizzle: L%8 selects XCD -> gh%8
        int g8 = L & 7; int rest = L >> 3;
        qt = rest & 15; gh = (rest >> 4) * 8 + g8;
    } else {
        qt = L & 15; gh = L >> 4;
    }
    int b = gh >> 1, h = gh & 1;

    // ---- stage Q (all 512 threads, one float4 each) ----
    {
        int r = t >> 3, d8 = (t & 7) * 8;
        size_t n = (size_t)b * SEQ + qt * 64 + r;
        *(float4*)&Qsh[r][d8] = *(const float4*)&qkv[n * QKVD + h * HDIM + d8];
    }
    // ---- prefetch this team's K/V tile 0 into regs ----
    const int NT  = SEQ / 128;          // tiles per team (8)
    const int kt0 = team * NT;
    int kr = tt >> 3, kd8 = (tt & 7) * 8;   // K: rows 0..31 (i=0), 32..63 (i=1)
    int vr = tt & 63, vdb = (tt >> 6) * 16; // V: key, d-base
    float4 kR[2], vR[2];
    {
        size_t nk0 = (size_t)b * SEQ + kt0 * 64 + kr;
        kR[0] = *(const float4*)&qkv[nk0 * QKVD + DIM + h * HDIM + kd8];
        kR[1] = *(const float4*)&qkv[(nk0 + 32) * QKVD + DIM + h * HDIM + kd8];
        size_t nv0 = (size_t)b * SEQ + kt0 * 64 + vr;
        vR[0] = *(const float4*)&qkv[nv0 * QKVD + 2 * DIM + h * HDIM + vdb];
        vR[1] = *(const float4*)&qkv[nv0 * QKVD + 2 * DIM + h * HDIM + vdb + 8];
    }
    __syncthreads();
    bf16x8 qa0 = *(const bf16x8*)&Qsh[w * 16 + l16][quad * 8];
    bf16x8 qa1 = *(const bf16x8*)&Qsh[w * 16 + l16][32 + quad * 8];

    f32x4 o[4] = {};
    float mrow[4] = {-1e30f, -1e30f, -1e30f, -1e30f};
    float lrow[4] = {};

#pragma unroll 1
    for (int kl = 0; kl < NT; ++kl) {
        // ---- regs -> LDS ----
        *(float4*)&Ksh[kr][kd8]      = kR[0];
        *(float4*)&Ksh[kr + 32][kd8] = kR[1];
        {
            const u16* pa = (const u16*)&vR[0];
            const u16* pb = (const u16*)&vR[1];
#pragma unroll
            for (int j = 0; j < 8; ++j) VshT[vdb + j][vr] = pa[j];
#pragma unroll
            for (int j = 0; j < 8; ++j) VshT[vdb + 8 + j][vr] = pb[j];
        }
        __syncthreads();
        if (kl + 1 < NT) {   // prefetch next tile (overlaps compute)
            size_t nk0 = (size_t)b * SEQ + (kt0 + kl + 1) * 64 + kr;
            kR[0] = *(const float4*)&qkv[nk0 * QKVD + DIM + h * HDIM + kd8];
            kR[1] = *(const float4*)&qkv[(nk0 + 32) * QKVD + DIM + h * HDIM + kd8];
            size_t nv0 = (size_t)b * SEQ + (kt0 + kl + 1) * 64 + vr;
            vR[0] = *(const float4*)&qkv[nv0 * QKVD + 2 * DIM + h * HDIM + vdb];
            vR[1] = *(const float4*)&qkv[nv0 * QKVD + 2 * DIM + h * HDIM + vdb + 8];
        }

        float sc[4][4];
#pragma unroll
        for (int c = 0; c < 4; ++c) {
            bf16x8 kb0 = *(const bf16x8*)&Ksh[c * 16 + l16][quad * 8];
            bf16x8 kb1 = *(const bf16x8*)&Ksh[c * 16 + l16][32 + quad * 8];
            f32x4 s = {};
            s = __builtin_amdgcn_mfma_f32_16x16x32_bf16(qa0, kb0, s, 0, 0, 0);
            s = __builtin_amdgcn_mfma_f32_16x16x32_bf16(qa1, kb1, s, 0, 0, 0);
#pragma unroll
            for (int r = 0; r < 4; ++r) sc[c][r] = s[r] * 0.125f;
        }
        float alpha[4];
#pragma unroll
        for (int r = 0; r < 4; ++r) {
            float mx = fmaxf(fmaxf(sc[0][r], sc[1][r]), fmaxf(sc[2][r], sc[3][r]));
#pragma unroll
            for (int off = 1; off < 16; off <<= 1)
                mx = fmaxf(mx, __shfl_xor(mx, off, 64));
            float mnew = fmaxf(mrow[r], mx);
            alpha[r] = __expf(mrow[r] - mnew);
            mrow[r] = mnew;
            float sum = 0.f;
#pragma unroll
            for (int c = 0; c < 4; ++c) {
                float p = __expf(sc[c][r] - mnew);
                sc[c][r] = p;
                sum += p;
            }
#pragma unroll
            for (int off = 1; off < 16; off <<= 1)
                sum += __shfl_xor(sum, off, 64);
            lrow[r] = lrow[r] * alpha[r] + sum;
        }
#pragma unroll
        for (int c = 0; c < 4; ++c)
#pragma unroll
            for (int r = 0; r < 4; ++r)
                Psh[w * 16 + quad * 4 + r][c * 16 + l16] = f2bf(sc[c][r]);
#pragma unroll
        for (int dt = 0; dt < 4; ++dt)
#pragma unroll
            for (int r = 0; r < 4; ++r) o[dt][r] *= alpha[r];
        bf16x8 pa0 = *(const bf16x8*)&Psh[w * 16 + l16][quad * 8];
        bf16x8 pa1 = *(const bf16x8*)&Psh[w * 16 + l16][32 + quad * 8];
#pragma unroll
        for (int dt = 0; dt < 4; ++dt) {
            bf16x8 vb0 = *(const bf16x8*)&VshT[dt * 16 + l16][quad * 8];
            bf16x8 vb1 = *(const bf16x8*)&VshT[dt * 16 + l16][32 + quad * 8];
            o[dt] = __builtin_amdgcn_mfma_f32_16x16x32_bf16(pa0, vb0, o[dt], 0, 0, 0);
            o[dt] = __builtin_amdgcn_mfma_f32_16x16x32_bf16(pa1, vb1, o[dt], 0, 0, 0);
        }
        __syncthreads();
    }

    // ---- merge team partials (team 1 -> LDS, team 0 combines + writes) ----
    if (team == 1) {
#pragma unroll
        for (int r = 0; r < 4; ++r) {
            int q = w * 16 + quad * 4 + r;
#pragma unroll
            for (int dt = 0; dt < 4; ++dt)
                Osh[q][dt * 16 + l16] = o[dt][r];
            if (l16 == 0) { Msh[q] = mrow[r]; Lsh[q] = lrow[r]; }
        }
    }
    __syncthreads();
    if (team == 0) {
#pragma unroll
        for (int r = 0; r < 4; ++r) {
            int q = w * 16 + quad * 4 + r;
            float m1 = Msh[q], l1 = Lsh[q];
            float M  = fmaxf(mrow[r], m1);
            float a0 = __expf(mrow[r] - M);
            float a1 = __expf(m1 - M);
            float inv = 1.f / (lrow[r] * a0 + l1 * a1);
            size_t n = (size_t)b * SEQ + qt * 64 + q;
#pragma unroll
            for (int dt = 0; dt < 4; ++dt)
                ctx[n * DIM + h * HDIM + dt * 16 + l16] =
                    f2bf((o[dt][r] * a0 + Osh[q][dt * 16 + l16] * a1) * inv);
        }
    }
}

// ---------------------------------------------------------------------------
extern "C" void kernel_launch(void* const* d_in, const int* in_sizes, int n_in,
                              void* d_out, int out_size, void* d_ws, size_t ws_size,
                              hipStream_t stream) {
    const void* x     = d_in[0];
    const void* pos   = d_in[1];
    const void* pe_w  = d_in[2];
    const void* pe_b  = d_in[3];
    const void* in_w  = d_in[4];
    const void* in_b  = d_in[5];
    const void* out_w = d_in[6];
    const void* out_b = d_in[7];
    const void* ln1_g = d_in[8];
    const void* ln1_b = d_in[9];
    const void* ln2_g = d_in[10];
    const void* ln2_b = d_in[11];
    const void* ff1_w = d_in[12];
    const void* ff1_b = d_in[13];
    const void* ff2_w = d_in[14];
    const void* ff2_b = d_in[15];

    char* wsb  = (char*)d_ws;
    int*  flag = (int*)(wsb + ((ws_size - 4) & ~(size_t)3));
    u16*  h01  = (u16*)d_out;   // h0 then h1, bf16 in dtype-dependent row slots
    const size_t MB = 1024 * 1024;

    detect_kernel<<<1, 1, 0, stream>>>((const u16*)x, flag);
    pe_kernel<<<NTOT / 2, 256, 0, stream>>>(x, pos, pe_w, pe_b, h01, flag);

    if (ws_size >= 17 * MB) {
        // batched path: qkv[0,12M), ctx[12M,16M); f1 reuses [0,16M)
        u16* qkv = (u16*)wsb;
        u16* ctx = (u16*)(wsb + 12 * MB);
        u16* f1  = (u16*)wsb;
        mgemm_kernel<0,1><<<dim3(NTOT / 64, 3), 256, 0, stream>>>(
            h01, in_w, in_b, nullptr, nullptr, nullptr, qkv,
            QKVD, -1, 0, 0, flag);
        attn_kernel<<<NGRAPH * NHEAD * 16, 512, 0, stream>>>(qkv, ctx);
        mgemm_kernel<2,1><<<dim3(NTOT / 64, 1), 256, 0, stream>>>(
            ctx, out_w, out_b, h01, ln1_g, ln1_b, h01,
            DIM, DIM, 0, 0, flag);
        mgemm_kernel<1,1><<<dim3(NTOT / 64, 4), 256, 0, stream>>>(
            h01, ff1_w, ff1_b, nullptr, nullptr, nullptr, f1,
            4 * DIM, -1, 0, 0, flag);
        mgemm_kernel<3,4><<<dim3(NTOT / 64, 1), 256, 0, stream>>>(
            f1, ff2_w, ff2_b, h01, ln2_g, ln2_b, d_out,
            DIM, 4 * DIM, 0, 0, flag);
    } else {
        // per-graph path: qkv_g[0,768K), ctx_g[768K,1M); f1_g reuses [0,1M)
        u16* qkv_g = (u16*)wsb;
        u16* ctx_g = (u16*)(wsb + 768 * 1024);
        u16* f1_g  = (u16*)wsb;
        for (int g = 0; g < NGRAPH; ++g) {
            int row0 = g * SEQ;
            mgemm_kernel<0,1><<<dim3(SEQ / 64, 3), 256, 0, stream>>>(
                h01, in_w, in_b, nullptr, nullptr, nullptr, qkv_g,
                QKVD, -1, row0, 0, flag);
            attn_kernel<<<NHEAD * 16, 512, 0, stream>>>(qkv_g, ctx_g);
            mgemm_kernel<2,1><<<dim3(SEQ / 64, 1), 256, 0, stream>>>(
                ctx_g, out_w, out_b, h01, ln1_g, ln1_b, h01,
                DIM, DIM, 0, row0, flag);
        }
        for (int g = 0; g < NGRAPH; ++g) {
            int row0 = g * SEQ;
            mgemm_kernel<1,1><<<dim3(SEQ / 64, 4), 256, 0, stream>>>(
                h01, ff1_w, ff1_b, nullptr, nullptr, nullptr, f1_g,
                4 * DIM, -1, row0, 0, flag);
            mgemm_kernel<3,4><<<dim3(SEQ / 64, 1), 256, 0, stream>>>(
                f1_g, ff2_w, ff2_b, h01, ln2_g, ln2_b, d_out,
                DIM, 4 * DIM, 0, row0, flag);
        }
    }
}

// Round 2
// 214.533 us; speedup vs baseline: 1.0558x; 1.0558x over previous
//
#include <hip/hip_runtime.h>

typedef unsigned short u16;

#define NGRAPH 16
#define SEQ    1024
#define DIM    128
#define NHEAD  2
#define HDIM   64
#define KPOS   20
#define NTOT   (NGRAPH*SEQ)     // 16384
#define QKVD   (3*DIM)          // 384

// ---------- bf16 helpers ----------------------------------------------------
__device__ __forceinline__ float bf2f(u16 u) {
    return __uint_as_float(((unsigned int)u) << 16);
}
__device__ __forceinline__ u16 f2bf(float f) {
    unsigned int u = __float_as_uint(f);
    u += 0x7fffu + ((u >> 16) & 1u);   // RNE
    return (u16)(u >> 16);
}

// ---------- DPP 16-lane reductions (VALU, keeps DS pipe free) --------------
// row_ror:n ctrl = 0x120|n ; reduce groups are contiguous 16-lane DPP rows.
template<int CTRL>
__device__ __forceinline__ float dpp_ror(float x) {
    return __int_as_float(__builtin_amdgcn_update_dpp(
        __float_as_int(x), __float_as_int(x), CTRL, 0xF, 0xF, true));
}
__device__ __forceinline__ float row16_max(float x) {
    x = fmaxf(x, dpp_ror<0x121>(x));
    x = fmaxf(x, dpp_ror<0x122>(x));
    x = fmaxf(x, dpp_ror<0x124>(x));
    x = fmaxf(x, dpp_ror<0x128>(x));
    return x;
}
__device__ __forceinline__ float row16_sum(float x) {
    x += dpp_ror<0x121>(x);
    x += dpp_ror<0x122>(x);
    x += dpp_ror<0x124>(x);
    x += dpp_ror<0x128>(x);
    return x;
}

// ---------- dtype-adaptive input loads (fbf=1: bf16, fbf=0: f32) -----------
__device__ __forceinline__ float ld1(const void* p, int fbf, size_t i) {
    return fbf ? bf2f(((const u16*)p)[i]) : ((const float*)p)[i];
}
// 8 contiguous weights -> packed bf16x8 (as float4 bit pattern)
__device__ __forceinline__ float4 ldw8(const void* W, int fbf, size_t i) {
    if (fbf) return *(const float4*)((const u16*)W + i);
    const float* q = (const float*)W + i;
    float4 a = *(const float4*)q, b = *(const float4*)(q + 4);
    float4 r;
    u16* d = (u16*)&r;
    d[0]=f2bf(a.x); d[1]=f2bf(a.y); d[2]=f2bf(a.z); d[3]=f2bf(a.w);
    d[4]=f2bf(b.x); d[5]=f2bf(b.y); d[6]=f2bf(b.z); d[7]=f2bf(b.w);
    return r;
}

// ---------- K0: dtype detection --------------------------------------------
__global__ void detect_kernel(const u16* __restrict__ x, int* __restrict__ flag) {
    if (threadIdx.x == 0 && blockIdx.x == 0) {
        int ok = 1;
        for (int i = 0; i < 256; i += 2) {
            unsigned e = (x[i] >> 7) & 0xFF;
            if (e < 60u || e > 180u) ok = 0;
        }
        *flag = ok;
    }
}

// ---------- K1: h0 = x + pos_enc @ pe_w.T + pe_b  (bf16, strided slots) ----
__global__ __launch_bounds__(256)
void pe_kernel(const void* __restrict__ x, const void* __restrict__ pos,
               const void* __restrict__ pe_w, const void* __restrict__ pe_b,
               u16* __restrict__ h0, const int* __restrict__ flag) {
    int fbf = *flag;
    __shared__ float wsh[DIM][KPOS + 1];
    int t = threadIdx.x;
    for (int i = t; i < DIM * KPOS; i += 256)
        wsh[i / KPOS][i % KPOS] = ld1(pe_w, fbf, i);
    __syncthreads();
    int row = blockIdx.x * 2 + (t >> 7), d = t & 127;
    float acc = 0.f;
#pragma unroll
    for (int k = 0; k < KPOS; ++k)
        acc += ld1(pos, fbf, (size_t)row * KPOS + k) * wsh[d][k];
    int rs = fbf ? 128 : 256;   // h0 row slot stride (u16 units)
    h0[(size_t)row * rs + d] =
        f2bf(ld1(x, fbf, (size_t)row * DIM + d) + acc + ld1(pe_b, fbf, d));
}

typedef __attribute__((ext_vector_type(8))) short bf16x8;
typedef __attribute__((ext_vector_type(4))) float f32x4;

// ---------- unified MFMA GEMM: out = A @ W^T (+epilogue) -------------------
// Block 256 = 4 waves; tile 64 rows x 128 cols; K staged 128 at a time
// (NK chunks of 128), register-prefetched. One barrier per chunk.
// EPI 0: +bias -> bf16 ws     EPI 1: +bias,relu -> bf16 ws
// EPI 2: +bias+resid+LN -> h01 slots   EPI 3: +bias+resid+LN -> final out
// A always bf16; AstrIn<0 means "h01 slot stride" (fbf?128:256).
template<int EPI, int NK>
__global__ __launch_bounds__(256)
void mgemm_kernel(const u16* __restrict__ A, const void* __restrict__ W,
                  const void* __restrict__ bias, const u16* __restrict__ resid,
                  const void* __restrict__ lng, const void* __restrict__ lnb,
                  void* __restrict__ outp, int Mtot, int AstrIn,
                  int arow0, int orow0, const int* __restrict__ flag) {
    const int K = NK * 128;
    int fbf  = *flag;
    int rs   = fbf ? 128 : 256;
    int Astr = (AstrIn < 0) ? rs : AstrIn;
    __shared__ u16 Ash[64][136];    // [row][k] (+8 pad)
    __shared__ u16 Wsh[128][136];   // [col][k]
    int t = threadIdx.x;
    int w = t >> 6, lane = t & 63, l16 = lane & 15, quad = lane >> 4;
    int n0 = blockIdx.x * 64;
    int m0 = blockIdx.y * 128;
    f32x4 acc[8] = {};
    float4 aR[4], wR[8];
    // prefetch chunk 0
#pragma unroll
    for (int i = 0; i < 4; ++i) {
        int idx = t + i * 256;
        int row = idx >> 4, k8 = (idx & 15) * 8;
        aR[i] = *(const float4*)&A[(size_t)(arow0 + n0 + row) * Astr + k8];
    }
#pragma unroll
    for (int i = 0; i < 8; ++i) {
        int idx = t + i * 256;
        int row = idx >> 4, k8 = (idx & 15) * 8;
        wR[i] = ldw8(W, fbf, (size_t)(m0 + row) * K + k8);
    }
#pragma unroll 1
    for (int c = 0; c < NK; ++c) {
        // regs -> LDS
#pragma unroll
        for (int i = 0; i < 4; ++i) {
            int idx = t + i * 256;
            *(float4*)&Ash[idx >> 4][(idx & 15) * 8] = aR[i];
        }
#pragma unroll
        for (int i = 0; i < 8; ++i) {
            int idx = t + i * 256;
            *(float4*)&Wsh[idx >> 4][(idx & 15) * 8] = wR[i];
        }
        __syncthreads();
        if (c + 1 < NK) {   // prefetch next chunk (overlaps MFMA below)
            int kc = (c + 1) * 128;
#pragma unroll
            for (int i = 0; i < 4; ++i) {
                int idx = t + i * 256;
                int row = idx >> 4, k8 = (idx & 15) * 8;
                aR[i] = *(const float4*)&A[(size_t)(arow0 + n0 + row) * Astr + kc + k8];
            }
#pragma unroll
            for (int i = 0; i < 8; ++i) {
                int idx = t + i * 256;
                int row = idx >> 4, k8 = (idx & 15) * 8;
                wR[i] = ldw8(W, fbf, (size_t)(m0 + row) * K + kc + k8);
            }
        }
#pragma unroll
        for (int kk = 0; kk < 4; ++kk) {
            bf16x8 af = *(const bf16x8*)&Ash[w * 16 + l16][kk * 32 + quad * 8];
#pragma unroll
            for (int s = 0; s < 8; ++s) {
                bf16x8 bf = *(const bf16x8*)&Wsh[s * 16 + l16][kk * 32 + quad * 8];
                acc[s] = __builtin_amdgcn_mfma_f32_16x16x32_bf16(af, bf, acc[s], 0, 0, 0);
            }
        }
        if (c + 1 < NK) __syncthreads();
    }
    // ---- epilogue ----
    float bb[8];
#pragma unroll
    for (int s = 0; s < 8; ++s) bb[s] = ld1(bias, fbf, m0 + s * 16 + l16);
    float gg[8], be[8];
    if (EPI >= 2) {
#pragma unroll
        for (int s = 0; s < 8; ++s) {
            gg[s] = ld1(lng, fbf, s * 16 + l16);
            be[s] = ld1(lnb, fbf, s * 16 + l16);
        }
    }
#pragma unroll
    for (int r = 0; r < 4; ++r) {
        int lr = w * 16 + quad * 4 + r;
        float v[8];
#pragma unroll
        for (int s = 0; s < 8; ++s) {
            v[s] = acc[s][r] + bb[s];
            if (EPI == 1) v[s] = fmaxf(v[s], 0.f);
        }
        if (EPI <= 1) {
            u16* o = (u16*)outp;
#pragma unroll
            for (int s = 0; s < 8; ++s)
                o[(size_t)(n0 + lr) * Mtot + m0 + s * 16 + l16] = f2bf(v[s]);
        } else {
            size_t rg = (size_t)(orow0 + n0 + lr);
#pragma unroll
            for (int s = 0; s < 8; ++s)
                v[s] += bf2f(resid[rg * rs + s * 16 + l16]);
            float sm = 0.f, sq = 0.f;
#pragma unroll
            for (int s = 0; s < 8; ++s) { sm += v[s]; sq += v[s] * v[s]; }
            sm = row16_sum(sm);
            sq = row16_sum(sq);
            float mu  = sm * (1.f / DIM);
            float var = fmaxf(sq * (1.f / DIM) - mu * mu, 0.f);
            float rsq = rsqrtf(var + 1e-5f);
            if (EPI == 2) {
                u16* o = (u16*)outp;
#pragma unroll
                for (int s = 0; s < 8; ++s)
                    o[rg * rs + s * 16 + l16] =
                        f2bf((v[s] - mu) * rsq * gg[s] + be[s]);
            } else {
                if (fbf) {
                    u16* o = (u16*)outp;
#pragma unroll
                    for (int s = 0; s < 8; ++s)
                        o[rg * 128 + s * 16 + l16] =
                            f2bf((v[s] - mu) * rsq * gg[s] + be[s]);
                } else {
                    float* o = (float*)outp;
#pragma unroll
                    for (int s = 0; s < 8; ++s)
                        o[rg * 128 + s * 16 + l16] =
                            (v[s] - mu) * rsq * gg[s] + be[s];
                }
            }
        }
    }
}

// ---------- K3: flash attention, MFMA bf16, pipelined K/V staging ----------
// 1D grid = ngh*16 blocks (ngh = graphs*heads). For ngh>=8, blockIdx is
// XCD-swizzled so all 16 q-tiles of one graph-head land on one XCD (its K/V
// then stays in that XCD's L2). Reg-prefetch of next K/V tile overlaps compute.
// R1 post-mortem: kernel is DS-pipe bound, not occupancy-bound (2x waves/CU
// made it SLOWER). So: softmax reductions moved from __shfl_xor (ds_swizzle,
// DS pipe + ~480cyc serial chains) to DPP row_ror (VALU). Q pre-scaled by
// 0.125 at stage (exact in bf16). setprio(1) around MFMA clusters.
__global__ __launch_bounds__(256)
void attn_kernel(const u16* __restrict__ qkv, u16* __restrict__ ctx) {
    __shared__ u16 Qsh[64][72];
    __shared__ u16 Ksh[64][72];
    __shared__ u16 VshT[64][72];
    __shared__ u16 Psh[64][72];
    int t    = threadIdx.x;
    int w    = t >> 6;
    int lane = t & 63;
    int l16  = lane & 15;
    int quad = lane >> 4;
    int L = blockIdx.x;
    int ngh = gridDim.x >> 4;
    int qt, gh;
    if (ngh >= 8) {           // XCD swizzle: L%8 selects XCD -> gh%8
        int g8 = L & 7; int rest = L >> 3;
        qt = rest & 15; gh = (rest >> 4) * 8 + g8;
    } else {
        qt = L & 15; gh = L >> 4;
    }
    int b = gh >> 1, h = gh & 1;

    // ---- stage Q, pre-scaled by 1/sqrt(hd)=0.125 (exact exponent shift) ----
#pragma unroll
    for (int i = 0; i < 2; ++i) {
        int idx = t + i * 256;
        int r = idx >> 3, d8 = (idx & 7) * 8;
        size_t n = (size_t)b * SEQ + qt * 64 + r;
        float4 qv = *(const float4*)&qkv[n * QKVD + h * HDIM + d8];
        u16* qp = (u16*)&qv;
#pragma unroll
        for (int j = 0; j < 8; ++j) qp[j] = f2bf(bf2f(qp[j]) * 0.125f);
        *(float4*)&Qsh[r][d8] = qv;
    }
    // ---- prefetch K/V tile 0 into regs ----
    int kr = t >> 3, kd8 = (t & 7) * 8;          // K: rows 0..31 (i=0), 32..63 (i=1)
    int vr = t & 63, vdb = (t >> 6) * 16;        // V: key, d-base
    float4 kR[2], vR[2];
    {
        size_t nk0 = (size_t)b * SEQ + kr;
        kR[0] = *(const float4*)&qkv[nk0 * QKVD + DIM + h * HDIM + kd8];
        kR[1] = *(const float4*)&qkv[(nk0 + 32) * QKVD + DIM + h * HDIM + kd8];
        size_t nv0 = (size_t)b * SEQ + vr;
        vR[0] = *(const float4*)&qkv[nv0 * QKVD + 2 * DIM + h * HDIM + vdb];
        vR[1] = *(const float4*)&qkv[nv0 * QKVD + 2 * DIM + h * HDIM + vdb + 8];
    }
    __syncthreads();
    bf16x8 qa0 = *(const bf16x8*)&Qsh[w * 16 + l16][quad * 8];
    bf16x8 qa1 = *(const bf16x8*)&Qsh[w * 16 + l16][32 + quad * 8];

    f32x4 o[4] = {};
    float mrow[4] = {-1e30f, -1e30f, -1e30f, -1e30f};
    float lrow[4] = {};

#pragma unroll 1
    for (int kt = 0; kt < SEQ / 64; ++kt) {
        // ---- regs -> LDS ----
        *(float4*)&Ksh[kr][kd8]      = kR[0];
        *(float4*)&Ksh[kr + 32][kd8] = kR[1];
        {
            const u16* pa = (const u16*)&vR[0];
            const u16* pb = (const u16*)&vR[1];
#pragma unroll
            for (int j = 0; j < 8; ++j) VshT[vdb + j][vr] = pa[j];
#pragma unroll
            for (int j = 0; j < 8; ++j) VshT[vdb + 8 + j][vr] = pb[j];
        }
        __syncthreads();
        if (kt + 1 < SEQ / 64) {   // prefetch next tile (overlaps compute)
            size_t nk0 = (size_t)b * SEQ + (kt + 1) * 64 + kr;
            kR[0] = *(const float4*)&qkv[nk0 * QKVD + DIM + h * HDIM + kd8];
            kR[1] = *(const float4*)&qkv[(nk0 + 32) * QKVD + DIM + h * HDIM + kd8];
            size_t nv0 = (size_t)b * SEQ + (kt + 1) * 64 + vr;
            vR[0] = *(const float4*)&qkv[nv0 * QKVD + 2 * DIM + h * HDIM + vdb];
            vR[1] = *(const float4*)&qkv[nv0 * QKVD + 2 * DIM + h * HDIM + vdb + 8];
        }

        float sc[4][4];
        __builtin_amdgcn_s_setprio(1);
#pragma unroll
        for (int c = 0; c < 4; ++c) {
            bf16x8 kb0 = *(const bf16x8*)&Ksh[c * 16 + l16][quad * 8];
            bf16x8 kb1 = *(const bf16x8*)&Ksh[c * 16 + l16][32 + quad * 8];
            f32x4 s = {};
            s = __builtin_amdgcn_mfma_f32_16x16x32_bf16(qa0, kb0, s, 0, 0, 0);
            s = __builtin_amdgcn_mfma_f32_16x16x32_bf16(qa1, kb1, s, 0, 0, 0);
#pragma unroll
            for (int r = 0; r < 4; ++r) sc[c][r] = s[r];
        }
        __builtin_amdgcn_s_setprio(0);
        float alpha[4];
#pragma unroll
        for (int r = 0; r < 4; ++r) {
            float mx = fmaxf(fmaxf(sc[0][r], sc[1][r]), fmaxf(sc[2][r], sc[3][r]));
            mx = row16_max(mx);
            float mnew = fmaxf(mrow[r], mx);
            alpha[r] = __expf(mrow[r] - mnew);
            mrow[r] = mnew;
            float sum = 0.f;
#pragma unroll
            for (int c = 0; c < 4; ++c) {
                float p = __expf(sc[c][r] - mnew);
                sc[c][r] = p;
                sum += p;
            }
            sum = row16_sum(sum);
            lrow[r] = lrow[r] * alpha[r] + sum;
        }
#pragma unroll
        for (int c = 0; c < 4; ++c)
#pragma unroll
            for (int r = 0; r < 4; ++r)
                Psh[w * 16 + quad * 4 + r][c * 16 + l16] = f2bf(sc[c][r]);
#pragma unroll
        for (int dt = 0; dt < 4; ++dt)
#pragma unroll
            for (int r = 0; r < 4; ++r) o[dt][r] *= alpha[r];
        bf16x8 pa0 = *(const bf16x8*)&Psh[w * 16 + l16][quad * 8];
        bf16x8 pa1 = *(const bf16x8*)&Psh[w * 16 + l16][32 + quad * 8];
        __builtin_amdgcn_s_setprio(1);
#pragma unroll
        for (int dt = 0; dt < 4; ++dt) {
            bf16x8 vb0 = *(const bf16x8*)&VshT[dt * 16 + l16][quad * 8];
            bf16x8 vb1 = *(const bf16x8*)&VshT[dt * 16 + l16][32 + quad * 8];
            o[dt] = __builtin_amdgcn_mfma_f32_16x16x32_bf16(pa0, vb0, o[dt], 0, 0, 0);
            o[dt] = __builtin_amdgcn_mfma_f32_16x16x32_bf16(pa1, vb1, o[dt], 0, 0, 0);
        }
        __builtin_amdgcn_s_setprio(0);
        __syncthreads();
    }
#pragma unroll
    for (int r = 0; r < 4; ++r) {
        float inv = 1.f / lrow[r];
        size_t n = (size_t)b * SEQ + qt * 64 + w * 16 + quad * 4 + r;
#pragma unroll
        for (int dt = 0; dt < 4; ++dt)
            ctx[n * DIM + h * HDIM + dt * 16 + l16] = f2bf(o[dt][r] * inv);
    }
}

// ---------------------------------------------------------------------------
extern "C" void kernel_launch(void* const* d_in, const int* in_sizes, int n_in,
                              void* d_out, int out_size, void* d_ws, size_t ws_size,
                              hipStream_t stream) {
    const void* x     = d_in[0];
    const void* pos   = d_in[1];
    const void* pe_w  = d_in[2];
    const void* pe_b  = d_in[3];
    const void* in_w  = d_in[4];
    const void* in_b  = d_in[5];
    const void* out_w = d_in[6];
    const void* out_b = d_in[7];
    const void* ln1_g = d_in[8];
    const void* ln1_b = d_in[9];
    const void* ln2_g = d_in[10];
    const void* ln2_b = d_in[11];
    const void* ff1_w = d_in[12];
    const void* ff1_b = d_in[13];
    const void* ff2_w = d_in[14];
    const void* ff2_b = d_in[15];

    char* wsb  = (char*)d_ws;
    int*  flag = (int*)(wsb + ((ws_size - 4) & ~(size_t)3));
    u16*  h01  = (u16*)d_out;   // h0 then h1, bf16 in dtype-dependent row slots
    const size_t MB = 1024 * 1024;

    detect_kernel<<<1, 1, 0, stream>>>((const u16*)x, flag);
    pe_kernel<<<NTOT / 2, 256, 0, stream>>>(x, pos, pe_w, pe_b, h01, flag);

    if (ws_size >= 17 * MB) {
        // batched path: qkv[0,12M), ctx[12M,16M); f1 reuses [0,16M)
        u16* qkv = (u16*)wsb;
        u16* ctx = (u16*)(wsb + 12 * MB);
        u16* f1  = (u16*)wsb;
        mgemm_kernel<0,1><<<dim3(NTOT / 64, 3), 256, 0, stream>>>(
            h01, in_w, in_b, nullptr, nullptr, nullptr, qkv,
            QKVD, -1, 0, 0, flag);
        attn_kernel<<<NGRAPH * NHEAD * 16, 256, 0, stream>>>(qkv, ctx);
        mgemm_kernel<2,1><<<dim3(NTOT / 64, 1), 256, 0, stream>>>(
            ctx, out_w, out_b, h01, ln1_g, ln1_b, h01,
            DIM, DIM, 0, 0, flag);
        mgemm_kernel<1,1><<<dim3(NTOT / 64, 4), 256, 0, stream>>>(
            h01, ff1_w, ff1_b, nullptr, nullptr, nullptr, f1,
            4 * DIM, -1, 0, 0, flag);
        mgemm_kernel<3,4><<<dim3(NTOT / 64, 1), 256, 0, stream>>>(
            f1, ff2_w, ff2_b, h01, ln2_g, ln2_b, d_out,
            DIM, 4 * DIM, 0, 0, flag);
    } else {
        // per-graph path: qkv_g[0,768K), ctx_g[768K,1M); f1_g reuses [0,1M)
        u16* qkv_g = (u16*)wsb;
        u16* ctx_g = (u16*)(wsb + 768 * 1024);
        u16* f1_g  = (u16*)wsb;
        for (int g = 0; g < NGRAPH; ++g) {
            int row0 = g * SEQ;
            mgemm_kernel<0,1><<<dim3(SEQ / 64, 3), 256, 0, stream>>>(
                h01, in_w, in_b, nullptr, nullptr, nullptr, qkv_g,
                QKVD, -1, row0, 0, flag);
            attn_kernel<<<NHEAD * 16, 256, 0, stream>>>(qkv_g, ctx_g);
            mgemm_kernel<2,1><<<dim3(SEQ / 64, 1), 256, 0, stream>>>(
                ctx_g, out_w, out_b, h01, ln1_g, ln1_b, h01,
                DIM, DIM, 0, row0, flag);
        }
        for (int g = 0; g < NGRAPH; ++g) {
            int row0 = g * SEQ;
            mgemm_kernel<1,1><<<dim3(SEQ / 64, 4), 256, 0, stream>>>(
                h01, ff1_w, ff1_b, nullptr, nullptr, nullptr, f1_g,
                4 * DIM, -1, row0, 0, flag);
            mgemm_kernel<3,4><<<dim3(SEQ / 64, 1), 256, 0, stream>>>(
                f1_g, ff2_w, ff2_b, h01, ln2_g, ln2_b, d_out,
                DIM, 4 * DIM, 0, row0, flag);
        }
    }
}